// Round 6
// baseline (182.404 us; speedup 1.0000x reference)
//
#include <hip/hip_runtime.h>
#include <math.h>

static constexpr int kM = 80;
static constexpr int kT = 4000;
static constexpr int kB = 64;
static constexpr int kLow = kM / 3;                 // 26
static constexpr int kHighStart = 2 * kM / 3;       // 53
static constexpr int kHighCount = kM - kHighStart;  // 27
static constexpr int kTrunc = 12;                   // A_ns^12 = 0.95^192 ~ 5e-5
#define EPSF 1e-6f
#define LOG2E 1.4426950408889634f

typedef float vfloat4 __attribute__((ext_vector_type(4)));
typedef float vfloat2 __attribute__((ext_vector_type(2)));

__device__ __forceinline__ float hw_exp2(float x) { return __builtin_amdgcn_exp2f(x); }
__device__ __forceinline__ float hw_log2(float x) { return __builtin_amdgcn_logf(x); }

__device__ __forceinline__ float fast_sigmoid(float x) {
    return __builtin_amdgcn_rcpf(1.0f + hw_exp2(-x * LOG2E));
}

// ---------------- Kernel A: gate[b,t] — float2 columns, split channels ------
// Block = 256 thr: 128 float2-columns x 2 channel-halves (h0: m 0..39 incl.
// low band; h1: m 40..79 incl. high band). 40 independent float2 loads per
// thread (wave = 64 x 8 B = 512 B/instr), one 3xfloat2 LDS exchange, h0
// finalizes. grid (16, 64) = 1024 blocks -> 4 blocks/CU, 16 waves/CU.
__global__ __launch_bounds__(256) void gate_kernel(
    const float* __restrict__ mel,
    const float* __restrict__ gate_temp,
    float* __restrict__ gate)
{
    const int tid = threadIdx.x;
    const int c   = tid & 127;          // float2-column within block
    const int h   = tid >> 7;           // channel half (wave-uniform)
    const int b   = blockIdx.y;
    const int col = blockIdx.x * 128 + c;           // float2-column index
    const bool valid = (col < kT / 2);              // last block partial

    const float* base = mel + (size_t)b * kM * kT + (size_t)col * 2;

    vfloat2 slog = {0.f,0.f}, ssum = {0.f,0.f}, sband = {0.f,0.f};
    if (valid) {
        if (h == 0) {
            #pragma unroll 10
            for (int m = 0; m < 40; ++m) {
                const vfloat2 v = *reinterpret_cast<const vfloat2*>(base + (size_t)m * kT);
                vfloat2 lg;
                lg.x = hw_log2(v.x + 1e-8f);
                lg.y = hw_log2(v.y + 1e-8f);
                slog += lg;
                ssum += v;
                if (m < kLow) sband += v;            // compile-time after unroll
            }
        } else {
            #pragma unroll 10
            for (int m = 40; m < 80; ++m) {
                const vfloat2 v = *reinterpret_cast<const vfloat2*>(base + (size_t)m * kT);
                vfloat2 lg;
                lg.x = hw_log2(v.x + 1e-8f);
                lg.y = hw_log2(v.y + 1e-8f);
                slog += lg;
                ssum += v;
                if (m >= kHighStart) sband += v;
            }
        }
    }

    __shared__ vfloat2 p1[3][128];      // h1 partials: slog, ssum, shigh (3 KB)
    if (h == 1) {
        p1[0][c] = slog; p1[1][c] = ssum; p1[2][c] = sband;
    }
    __syncthreads();

    if (h == 0 && valid) {
        const vfloat2 tlog  = slog + p1[0][c];
        const vfloat2 tsum  = ssum + p1[1][c];
        const vfloat2 thigh = p1[2][c];
        const vfloat2 tlow  = sband;

        const float gt = gate_temp[0];
        vfloat2 o;
        #pragma unroll
        for (int q = 0; q < 2; ++q) {
            const float sl = (q == 0) ? tlog.x  : tlog.y;
            const float ss = (q == 0) ? tsum.x  : tsum.y;
            const float lo = (q == 0) ? tlow.x  : tlow.y;
            const float hi = (q == 0) ? thigh.x : thigh.y;
            const float geo   = hw_exp2(sl * (1.0f / kM));
            const float arith = ss * (1.0f / kM) + 1e-8f;
            float sf = geo * __builtin_amdgcn_rcpf(arith);
            sf = fminf(fmaxf(sf, 0.0f), 1.0f);
            const float low  = lo * (1.0f / kLow);
            const float high = hi * (1.0f / kHighCount);
            float tilt = low * __builtin_amdgcn_rcpf(low + high + 1e-8f);
            tilt = fminf(fmaxf(tilt, 0.0f), 1.0f);
            const float sfa = sf + (1.0f - sf) * fmaxf(tilt - 0.6f, 0.0f);
            const float g = fast_sigmoid(gt * (sfa - 0.5f));
            if (q == 0) o.x = g; else o.y = g;
        }
        *reinterpret_cast<vfloat2*>(gate + (size_t)b * kT + (size_t)col * 2) = o;
    }
}

// ---------------- Kernel B: dual PCEN — chunk-B carry + ILP trans -----------
// Block per (b,m) row. Thread i owns 16 contiguous elements. Carry via the
// data-independent chunk transform (A = a^16 per-row constant):
//   carry_i = sum_{k<12} A^k B_{i-1-k} (+ A^i x0 exactly for i<=12).
// Main pass restructured for ILP: the ONLY serial part of PCEN is the cheap
// pk_fma recurrence, so compute 8 sm values first (8 serial fma ~30 cyc),
// THEN run 8 INDEPENDENT 4-deep transcendental chains. This breaks the
// ~1000-cycle serial log->exp->log->exp chain the fused loop had (the
// round-2 "VALUBusy 41%, nothing saturated" signature).
__global__ __launch_bounds__(256) void pcen_kernel(
    const float* __restrict__ mel,
    const float* __restrict__ ls_ns, const float* __restrict__ la_ns,
    const float* __restrict__ ld_ns, const float* __restrict__ lr_ns,
    const float* __restrict__ ls_st, const float* __restrict__ la_st,
    const float* __restrict__ ld_st, const float* __restrict__ lr_st,
    const float* __restrict__ gate,
    float* __restrict__ out)
{
    const int m = blockIdx.x;
    const int b = blockIdx.y;

    const float s_ns     = fminf(fmaxf(fast_sigmoid(ls_ns[m]), 0.05f), 0.3f);
    const float alpha_ns = fminf(fmaxf(fast_sigmoid(la_ns[m]), 0.9f), 0.999f);
    const float delta_ns = fminf(fmaxf(hw_exp2(ld_ns[m] * LOG2E), 0.5f), 5.0f);
    const float r_ns     = fminf(fmaxf(fast_sigmoid(lr_ns[m]), 0.05f), 0.25f);
    const float s_st     = fminf(fmaxf(fast_sigmoid(ls_st[m]), 0.05f), 0.3f);
    const float alpha_st = fminf(fmaxf(fast_sigmoid(la_st[m]), 0.9f), 0.999f);
    const float delta_st = fminf(fmaxf(hw_exp2(ld_st[m] * LOG2E), 0.001f), 0.1f);
    const float r_st     = fminf(fmaxf(fast_sigmoid(lr_st[m]), 0.05f), 0.25f);
    const float dr_ns = hw_exp2(r_ns * hw_log2(delta_ns));   // delta^r
    const float dr_st = hw_exp2(r_st * hw_log2(delta_st));

    const vfloat2 a2 = {1.0f - s_ns, 1.0f - s_st};
    const vfloat2 s2 = {s_ns, s_st};
    const vfloat2 d2 = {delta_ns, delta_st};
    const float man = -alpha_ns, mas = -alpha_st;

    const size_t rowoff = ((size_t)b * kM + m) * kT;
    const float* row = mel + rowoff;

    const int i  = threadIdx.x;         // chunk index
    const int t0 = i * 16;
    const bool valid = (t0 < kT);       // tids 250..255 idle

    float x[16];
    float gv[16];
    if (valid) {
        const float4* p = reinterpret_cast<const float4*>(row + t0);
        #pragma unroll
        for (int q = 0; q < 4; ++q) {
            const float4 v = p[q];
            x[4*q+0] = v.x; x[4*q+1] = v.y; x[4*q+2] = v.z; x[4*q+3] = v.w;
        }
        const float4* gp = reinterpret_cast<const float4*>(gate + (size_t)b * kT + t0);
        #pragma unroll
        for (int q = 0; q < 4; ++q) {
            const float4 v = gp[q];
            gv[4*q+0] = v.x; gv[4*q+1] = v.y; gv[4*q+2] = v.z; gv[4*q+3] = v.w;
        }
    } else {
        #pragma unroll
        for (int k = 0; k < 16; ++k) { x[k] = 0.0f; gv[k] = 0.0f; }
    }

    __shared__ float sv0;
    if (i == 0) sv0 = x[0];

    // local chunk offset B_i (16 serial pk_fma); transform is v -> A*v + B_i
    vfloat2 Bv = {0.0f, 0.0f};
    #pragma unroll
    for (int k = 0; k < 16; ++k) {
        Bv = a2 * Bv + s2 * x[k];       // v_pk_fma_f32
    }
    const vfloat2 p2  = a2 * a2;
    const vfloat2 p4  = p2 * p2;
    const vfloat2 p8  = p4 * p4;
    const vfloat2 A2  = p8 * p8;        // a^16 (data-independent)

    __shared__ vfloat2 Btab[256];
    Btab[i] = Bv;
    __syncthreads();

    // carry: sm = sum_{k=0}^{11} A^k B_{i-1-k}  (+ A^i x0 exactly if i<=12)
    vfloat2 sm = {0.0f, 0.0f};
    vfloat2 pw = {1.0f, 1.0f};
    #pragma unroll
    for (int k = 0; k < kTrunc; ++k) {
        const vfloat2 Bk = Btab[(i - 1 - k) & 255];
        if (k < i) {
            sm = pw * Bk + sm;
            pw = pw * A2;
        }
    }
    if (i <= kTrunc) {
        const float x0 = sv0;
        const vfloat2 x02 = {x0, x0};
        sm = pw * x02 + sm;             // pw = A^i here; exact init term
    }

    // ---- main pass: peel the serial recurrence off the trans chains ----
    if (valid) {
        float4* op = reinterpret_cast<float4*>(out + rowoff + t0);
        #pragma unroll
        for (int h = 0; h < 2; ++h) {
            // serial part: 8 pk_fma (only true dependency in PCEN)
            vfloat2 smv[8];
            #pragma unroll
            for (int j = 0; j < 8; ++j) {
                sm = a2 * sm + s2 * x[8*h + j];    // v_pk_fma_f32
                smv[j] = sm;
            }
            // parallel part: 8 independent 4-deep trans chains (full ILP)
            float res[8];
            #pragma unroll
            for (int j = 0; j < 8; ++j) {
                const int k = 8*h + j;
                const float xv = x[k];
                vfloat2 g2;
                g2.x = hw_exp2(man * hw_log2(smv[j].x + EPSF));
                g2.y = hw_exp2(mas * hw_log2(smv[j].y + EPSF));
                const vfloat2 u2 = g2 * xv + d2;   // v_pk_fma_f32
                const float on = hw_exp2(r_ns * hw_log2(u2.x)) - dr_ns;
                const float os = hw_exp2(r_st * hw_log2(u2.y)) - dr_st;
                res[j] = fmaf(gv[k], os - on, on);
            }
            #pragma unroll
            for (int q = 0; q < 2; ++q) {
                float4 v;
                v.x = res[4*q+0]; v.y = res[4*q+1];
                v.z = res[4*q+2]; v.w = res[4*q+3];
                op[2*h + q] = v;                    // plain cached stores
            }
        }
    }
}

extern "C" void kernel_launch(void* const* d_in, const int* in_sizes, int n_in,
                              void* d_out, int out_size, void* d_ws, size_t ws_size,
                              hipStream_t stream)
{
    const float* mel       = (const float*)d_in[0];
    const float* ls_ns     = (const float*)d_in[1];
    const float* la_ns     = (const float*)d_in[2];
    const float* ld_ns     = (const float*)d_in[3];
    const float* lr_ns     = (const float*)d_in[4];
    const float* ls_st     = (const float*)d_in[5];
    const float* la_st     = (const float*)d_in[6];
    const float* ld_st     = (const float*)d_in[7];
    const float* lr_st     = (const float*)d_in[8];
    const float* gate_temp = (const float*)d_in[9];
    float* out  = (float*)d_out;
    float* gate = (float*)d_ws;   // kB*kT floats = 1.02 MB scratch

    dim3 gA((kT / 2 + 127) / 128, kB);   // (16, 64) = 1024 blocks, 16 waves/CU
    gate_kernel<<<gA, 256, 0, stream>>>(mel, gate_temp, gate);

    dim3 gB(kM, kB);                     // 5120 blocks, one (b,m) row each
    pcen_kernel<<<gB, 256, 0, stream>>>(mel, ls_ns, la_ns, ld_ns, lr_ns,
                                        ls_st, la_st, ld_st, lr_st, gate, out);
}